// Round 9
// baseline (358.969 us; speedup 1.0000x reference)
//
#include <hip/hip_runtime.h>
#include <cstdint>
#include <cstddef>

// ---------------- types ----------------
typedef __bf16 bf16x8 __attribute__((ext_vector_type(8)));
typedef float  floatx4 __attribute__((ext_vector_type(4)));
typedef unsigned short ushortx8 __attribute__((ext_vector_type(8)));
typedef unsigned short ushortx4 __attribute__((ext_vector_type(4)));

#define MFMA16(a, b, c) __builtin_amdgcn_mfma_f32_16x16x32_bf16((a), (b), (c), 0, 0, 0)

__device__ inline unsigned short f2bf(float f) {
    unsigned int u = __float_as_uint(f);
    unsigned int r = (u + 0x7fffu + ((u >> 16) & 1u)) >> 16;
    return (unsigned short)r;
}

// ---------------- merged convert: activations (2 tensors) + weights (7) ----------------
struct SrcAll { const float* a[2]; const float* w[7]; };
__global__ __launch_bounds__(256) void k_conv(SrcAll s, unsigned short* __restrict__ adst,
                                              unsigned short* __restrict__ wdst) {
    int bid = blockIdx.x;
    if (bid < 4096) {               // activations: 1M i-units, 8 f32 each
        int i = bid * 256 + threadIdx.x;
        const float* src = s.a[i >> 19];
        int off = i & 524287;
        const float4* p = (const float4*)src + (size_t)off * 2;
        float4 x0 = p[0], x1 = p[1];
        ushortx8 o;
        o[0] = f2bf(x0.x); o[1] = f2bf(x0.y); o[2] = f2bf(x0.z); o[3] = f2bf(x0.w);
        o[4] = f2bf(x1.x); o[5] = f2bf(x1.y); o[6] = f2bf(x1.z); o[7] = f2bf(x1.w);
        *((ushortx8*)adst + i) = o;
    } else {                        // weights: 917504 i-units
        int i = (bid - 4096) * 256 + threadIdx.x;
        const float* src = s.w[i >> 17];
        int off = i & 131071;
        const float4* p = (const float4*)src + (size_t)off * 2;
        float4 x0 = p[0], x1 = p[1];
        ushortx8 o;
        o[0] = f2bf(x0.x); o[1] = f2bf(x0.y); o[2] = f2bf(x0.z); o[3] = f2bf(x0.w);
        o[4] = f2bf(x1.x); o[5] = f2bf(x1.y); o[6] = f2bf(x1.z); o[7] = f2bf(x1.w);
        *((ushortx8*)wdst + i) = o;
    }
}

// ---------------- GEMM: C[M][Nc] = A[M][K] @ W[Nc][K]^T + bias ----------------
// ROUND-2 VERIFIED SYNC STRUCTURE (frozen): reg-staged prefetch issued right
// after the compute barrier. DMA variants (r3/r4/r6) regressed or crashed;
// f32-A fusion (r5) regressed.
// Round-9: LDS XOR-swizzle on BOTH write and read sides (reg-staged, so rule
// #21 is satisfiable). Layout: element (row R, 16B col C, k-half) lives at
// byte khalf*8192 + R*64 + ((C ^ ((R>>1)&3))<<4). Read side key (R>>1)&3 ==
// (l15>>1)&3 (wm*32, r*8 === 0 mod 4) -> single per-lane constant; write side
// key == (tid>>3)&3. Fixes the 8-lanes-per-bank-group fragment-read conflict
// (SQ_LDS_BANK_CONFLICT 3.1M/dispatch, ~12% of cycles).
// MODE 0: fused QKV packs; MODE 3: f32 row-major; MODE 4: fused cross QKV
// (sect 0 uses A, sects 1-2 use A2).
// Pack layouts: Q/K[b][h][l][64] bf16; V[b][h][l/32][d(64)][l%32] bf16.
// XCD swizzle: XCD (fid&7) owns a 4-m-tile stripe; streams the W n-tiles.
template <int MODE>
__global__ __launch_bounds__(256) void k_gemm_bias(const unsigned short* __restrict__ A,
                                                   const unsigned short* __restrict__ A2,
                                                   const unsigned short* __restrict__ W,
                                                   const float* __restrict__ bias0,
                                                   const float* __restrict__ bias1,
                                                   const float* __restrict__ bias2,
                                                   void* __restrict__ d0,
                                                   void* __restrict__ d1,
                                                   void* __restrict__ d2,
                                                   int K) {
    __shared__ __align__(16) unsigned short As[128 * 64];   // 16 KB
    __shared__ __align__(16) unsigned short Bs[128 * 64];   // 16 KB
    const int tid = threadIdx.x;
    const int wave = tid >> 6, lane = tid & 63;
    const int quad = lane >> 4, l15 = lane & 15;
    const int wm = wave >> 1, wn = wave & 1;

    constexpr int NT = (MODE == 3) ? 8 : 24;     // n-tiles in grid
    int fid = blockIdx.y * 32 + blockIdx.x;
    int xcd = fid & 7, idx = fid >> 3;
    const int m0 = (xcd * 4 + idx / NT) * 128;
    const int n0 = (idx % NT) * 128;
    const int sect_blk = n0 >> 10;

    const unsigned short* Ause = (MODE == 4 && sect_blk != 0) ? A2 : A;

    const size_t rowbytes = (size_t)K * 2;
    const int idx0 = tid, idx1 = 256 + tid;
    const char* pA0 = (const char*)Ause + (size_t)(m0 + (idx0 >> 2)) * rowbytes + ((idx0 & 3) << 4);
    const char* pA1 = (const char*)Ause + (size_t)(m0 + (idx1 >> 2)) * rowbytes + ((idx1 & 3) << 4);
    const char* pB0 = (const char*)W + (size_t)(n0 + (idx0 >> 2)) * rowbytes + ((idx0 & 3) << 4);
    const char* pB1 = (const char*)W + (size_t)(n0 + (idx1 >> 2)) * rowbytes + ((idx1 & 3) << 4);

    int4 a0a = *(const int4*)pA0, a0b = *(const int4*)(pA0 + 64);
    int4 a1a = *(const int4*)pA1, a1b = *(const int4*)(pA1 + 64);
    int4 b0a = *(const int4*)pB0, b0b = *(const int4*)(pB0 + 64);
    int4 b1a = *(const int4*)pB1, b1b = *(const int4*)(pB1 + 64);

    floatx4 acc[4][4] = {};

    // swizzled staging byte offsets (write side): row = tid>>2 (+64 for idx1),
    // C = tid&3, key = (row>>1)&3 = (tid>>3)&3 (same for idx1: +64 keeps key)
    const int woff0 = (tid >> 2) * 64 + ((((tid & 3) ^ ((tid >> 3) & 3))) << 4);
    const int woff1 = woff0 + 4096;            // rows 64..127
    char* AsB = (char*)As;
    char* BsB = (char*)Bs;

    // swizzled fragment read column slot (read side): key = (l15>>1)&3
    const int qswA = ((quad ^ ((l15 >> 1) & 3)) << 4);

    const int KT = K >> 6;   // 16
    for (int kt = 0; kt < KT; ++kt) {
        __syncthreads();
        *(int4*)(AsB + woff0) = a0a; *(int4*)(AsB + woff1) = a1a;
        *(int4*)(AsB + 8192 + woff0) = a0b; *(int4*)(AsB + 8192 + woff1) = a1b;
        *(int4*)(BsB + woff0) = b0a; *(int4*)(BsB + woff1) = b1a;
        *(int4*)(BsB + 8192 + woff0) = b0b; *(int4*)(BsB + 8192 + woff1) = b1b;
        __syncthreads();
        if (kt + 1 < KT) {   // prefetch next K-tile (in flight across the MFMAs)
            pA0 += 128; pA1 += 128; pB0 += 128; pB1 += 128;
            a0a = *(const int4*)pA0; a0b = *(const int4*)(pA0 + 64);
            a1a = *(const int4*)pA1; a1b = *(const int4*)(pA1 + 64);
            b0a = *(const int4*)pB0; b0b = *(const int4*)(pB0 + 64);
            b1a = *(const int4*)pB1; b1b = *(const int4*)(pB1 + 64);
        }
        const char* Asb = (const char*)As;
        const char* Bsb = (const char*)Bs;
#pragma unroll
        for (int half = 0; half < 2; ++half) {
            const int hb = half * 8192;
            bf16x8 af[4], bfr[4];
#pragma unroll
            for (int r = 0; r < 4; ++r)
                af[r] = *(const bf16x8*)(Asb + hb + (wm * 64 + r * 16 + l15) * 64 + qswA);
#pragma unroll
            for (int c = 0; c < 4; ++c)
                bfr[c] = *(const bf16x8*)(Bsb + hb + (wn * 64 + c * 16 + l15) * 64 + qswA);
#pragma unroll
            for (int r = 0; r < 4; ++r)
#pragma unroll
                for (int c = 0; c < 4; ++c)
                    acc[r][c] = MFMA16(af[r], bfr[c], acc[r][c]);
        }
    }

    // epilogue: C row = quad*4+i, col = l15
#pragma unroll
    for (int c = 0; c < 4; ++c) {
        int col = n0 + wn * 64 + c * 16 + l15;
        int sect = col >> 10, cc = col & 1023;
        float bv;
        if (MODE == 3) bv = bias0[col];
        else bv = (sect == 0 ? bias0 : (sect == 1 ? bias1 : bias2))[cc];
        int h = cc >> 6, d = cc & 63;
#pragma unroll
        for (int r = 0; r < 4; ++r) {
            int mrow = m0 + wm * 64 + r * 16 + quad * 4;
#pragma unroll
            for (int i = 0; i < 4; ++i) {
                float v = acc[r][c][i] + bv;
                int row = mrow + i;
                if (MODE == 3) {
                    ((float*)d0)[(size_t)row * 1024 + col] = v;
                } else {
                    int b = row >> 10, l = row & 1023;
                    unsigned short* base = (unsigned short*)(sect == 0 ? d0 : (sect == 1 ? d1 : d2));
                    bool isV = (sect == 2);
                    size_t off;
                    if (isV) {
                        int kk = l & 31;   // natural key order
                        off = (size_t)(b * 16 + h) * 65536 + (size_t)(l >> 5) * 2048 + d * 32 + kk;
                    } else {
                        off = ((size_t)(b * 16 + h) * 1024 + l) * 64 + d;
                    }
                    base[off] = f2bf(v);
                }
            }
        }
    }
}

// ---------------- flash attention v9 ----------------
// Qp,Kp: [b][h][1024][64] bf16; Vp: [b][h][32][64][32] bf16; mask: [b][1024] f32.
// v9 = v5's geometry (32 q-rows/wave, grid 512) x v7's in-register softmax
// (swapped QK^T + permlane P-transpose, no Plds). v8 (no LDS) proved staging
// is needed (95us latency-bound). K/V double-buffered, one __syncthreads per
// tile. LDS = 2x8K (K, XOR-swizzled) + 2x10K (V, 80B rows) + 4K (penf) = 40KB.
// f bits [g:3][q:3][x:3]: bh = x + 8g (XCD-pinned), qt = (q+g)&7, causal
// ktiles = 2qt+2 with wave-level and half-level skips.
__global__ __launch_bounds__(256, 2) void k_flash_attn(const unsigned short* __restrict__ Qp,
                                                       const unsigned short* __restrict__ Kp,
                                                       const unsigned short* __restrict__ Vp,
                                                       const float* __restrict__ mask,
                                                       float* __restrict__ ctx,
                                                       int causal) {
    const int L = 1024, D = 1024;
    const float SC = 0.18033688011112042f;      // 0.125 * log2(e)
    int f = blockIdx.x;                          // 0..511
    int g = f >> 6;                              // 0..7
    int bh = (f & 7) + (g << 3);                 // 0..63, XCD-pinned K/V
    int qt = ((f >> 3) + g) & 7;                 // causal balance spread
    int h = bh & 15, b = bh >> 4;
    int tid = threadIdx.x;
    int wave = tid >> 6, lane = tid & 63, quad = lane >> 4, l15 = lane & 15;
    int qbase = qt * 128 + wave * 32;            // 32 q rows per wave

    __shared__ __align__(16) unsigned short Ks[2 * 4096];   // 16 KB, XOR-swizzled rows
    __shared__ __align__(16) unsigned short Vs[2 * 5120];   // 20 KB, rows padded 80B
    __shared__ float penf[1024];                            // 4 KB

    {   // mask penalty, pre-scaled for exp2
        float4 mv = ((const float4*)(mask + b * L))[tid];
        float4 pv;
        pv.x = (1.0f - mv.x) * -14426.950408889634f;
        pv.y = (1.0f - mv.y) * -14426.950408889634f;
        pv.z = (1.0f - mv.z) * -14426.950408889634f;
        pv.w = (1.0f - mv.w) * -14426.950408889634f;
        ((float4*)penf)[tid] = pv;
    }

    // Q fragments: 32 q rows = 2 halves x 2 d-chunks
    const unsigned short* Qh = Qp + ((size_t)(b * 16 + h) * 1024 + qbase) * 64;
    bf16x8 qf[2][2];
#pragma unroll
    for (int qh = 0; qh < 2; ++qh) {
        qf[qh][0] = *(const bf16x8*)(Qh + (qh * 16 + l15) * 64 + quad * 8);
        qf[qh][1] = *(const bf16x8*)(Qh + (qh * 16 + l15) * 64 + 32 + quad * 8);
    }

    const char* Kh = (const char*)(Kp + (size_t)(b * 16 + h) * 65536);
    const char* Vh = (const char*)(Vp + (size_t)(b * 16 + h) * 65536);

    int ktiles = causal ? (2 * qt + 2) : 16;   // block-uniform

    // staging dests (within one buffer)
    int krow = tid >> 3, kblk = tid & 7;
    int kd0 = krow * 128 + ((kblk ^ (krow & 7)) << 4);
    int kd1 = kd0 + 4096;
    int vd0 = (tid >> 2) * 80 + ((tid & 3) << 4);
    int vd1 = vd0 + 5120;

    // fragment read offsets (within one buffer)
    int karA[4], karB[4];
#pragma unroll
    for (int r = 0; r < 4; ++r) {
        int row = r * 16 + l15;
        karA[r] = row * 128 + ((quad ^ (l15 & 7)) << 4);
        karB[r] = row * 128 + (((quad | 4) ^ (l15 & 7)) << 4);
    }
    int var_[8];
#pragma unroll
    for (int s = 0; s < 2; ++s)
#pragma unroll
        for (int fi = 0; fi < 4; ++fi)
            var_[s * 4 + fi] = s * 5120 + (fi * 16 + l15) * 80 + (quad << 4);

    floatx4 O[2][4] = {};
    float lsum[2] = {0.0f, 0.0f};

    // prologue: load + stage tile 0 into buffer 0
    int4 ka0 = *(const int4*)(Kh + tid * 16);
    int4 ka1 = *(const int4*)(Kh + 4096 + tid * 16);
    int4 va0 = *(const int4*)(Vh + tid * 16);
    int4 va1 = *(const int4*)(Vh + 4096 + tid * 16);
    {
        char* Kw = (char*)Ks;
        char* Vw = (char*)Vs;
        *(int4*)(Kw + kd0) = ka0;
        *(int4*)(Kw + kd1) = ka1;
        *(int4*)(Vw + vd0) = va0;
        *(int4*)(Vw + vd1) = va1;
    }
    __syncthreads();

    for (int kt = 0; kt < ktiles; ++kt) {
        const char* Ksb = (const char*)Ks + (size_t)(kt & 1) * 8192;
        const char* Vsb = (const char*)Vs + (size_t)(kt & 1) * 10240;
        int k0 = kt * 64;
        bool last = (kt + 1 >= ktiles);
        bool vis = !(causal && k0 > qbase + 31);   // wave-uniform: any visible keys?

        bf16x8 kA[4], kB[4], vv[8];
        if (vis) {
#pragma unroll
            for (int r = 0; r < 4; ++r) {
                kA[r] = *(const bf16x8*)(Ksb + karA[r]);
                kB[r] = *(const bf16x8*)(Ksb + karB[r]);
            }
#pragma unroll
            for (int s = 0; s < 8; ++s) vv[s] = *(const bf16x8*)(Vsb + var_[s]);
        }

        // prefetch next tile into regs (latency hidden under compute)
        if (!last) {
            const char* Kg = Kh + (size_t)(kt + 1) * 8192;
            const char* Vg = Vh + (size_t)(kt + 1) * 8192;
            ka0 = *(const int4*)(Kg + tid * 16);
            ka1 = *(const int4*)(Kg + 4096 + tid * 16);
            va0 = *(const int4*)(Vg + tid * 16);
            va1 = *(const int4*)(Vg + 4096 + tid * 16);
        }

        if (vis) {
#pragma unroll
            for (int qh = 0; qh < 2; ++qh) {
                int qlo = qbase + qh * 16;
                if (causal && k0 > qlo + 15) continue;       // half fully masked
                bool boundary = causal && (k0 + 63 > qlo);
                int qv = qlo + l15;

                // swapped QK^T: T[s] rows = keys 16s.., cols = q (lane l15)
                floatx4 T[4] = {};
                T[0] = MFMA16(kA[0], qf[qh][0], T[0]); T[0] = MFMA16(kB[0], qf[qh][1], T[0]);
                T[1] = MFMA16(kA[1], qf[qh][0], T[1]); T[1] = MFMA16(kB[1], qf[qh][1], T[1]);
                T[2] = MFMA16(kA[2], qf[qh][0], T[2]); T[2] = MFMA16(kB[2], qf[qh][1], T[2]);
                T[3] = MFMA16(kA[3], qf[qh][0], T[3]); T[3] = MFMA16(kB[3], qf[qh][1], T[3]);

                // softmax, fully lane-local; pack P to bf16 pairs per key-group s
                unsigned w_[4][2];
#pragma unroll
                for (int s = 0; s < 4; ++s) {
                    floatx4 pr = *(const floatx4*)(penf + k0 + 16 * s + quad * 4);
                    unsigned rr[4];
#pragma unroll
                    for (int i = 0; i < 4; ++i) {
                        float x = fmaf(T[s][i], SC, pr[i]);
                        if (boundary) {
                            int key = k0 + 16 * s + quad * 4 + i;
                            x = (key <= qv) ? x : -50000.0f;
                        }
                        float p = __builtin_amdgcn_exp2f(x);
                        lsum[qh] += p;
                        rr[i] = __float_as_uint(p) + 0x8000u;
                    }
                    w_[s][0] = __builtin_amdgcn_perm(rr[1], rr[0], 0x07060302u);
                    w_[s][1] = __builtin_amdgcn_perm(rr[3], rr[2], 0x07060302u);
                }

                // in-register transpose of P into PV A-fragment layout
                unsigned a00 = w_[0][0], a10 = w_[1][0];
                unsigned a01 = w_[0][1], a11 = w_[1][1];
                unsigned a20 = w_[2][0], a30 = w_[3][0];
                unsigned a21 = w_[2][1], a31 = w_[3][1];
                asm("v_permlane32_swap_b32 %0, %1" : "+v"(a00), "+v"(a10));
                asm("v_permlane32_swap_b32 %0, %1" : "+v"(a01), "+v"(a11));
                asm("v_permlane32_swap_b32 %0, %1" : "+v"(a20), "+v"(a30));
                asm("v_permlane32_swap_b32 %0, %1" : "+v"(a21), "+v"(a31));
                asm("v_permlane16_swap_b32 %0, %1" : "+v"(a00), "+v"(a10));
                asm("v_permlane16_swap_b32 %0, %1" : "+v"(a01), "+v"(a11));
                asm("v_permlane16_swap_b32 %0, %1" : "+v"(a20), "+v"(a30));
                asm("v_permlane16_swap_b32 %0, %1" : "+v"(a21), "+v"(a31));
                union PU { unsigned u[4]; bf16x8 v; };
                PU pl, ph;
                pl.u[0] = a00; pl.u[1] = a01; pl.u[2] = a10; pl.u[3] = a11;   // keys 0..31
                ph.u[0] = a20; ph.u[1] = a21; ph.u[2] = a30; ph.u[3] = a31;   // keys 32..63

                O[qh][0] = MFMA16(pl.v, vv[0], O[qh][0]);
                O[qh][1] = MFMA16(pl.v, vv[1], O[qh][1]);
                O[qh][2] = MFMA16(pl.v, vv[2], O[qh][2]);
                O[qh][3] = MFMA16(pl.v, vv[3], O[qh][3]);
                O[qh][0] = MFMA16(ph.v, vv[4], O[qh][0]);
                O[qh][1] = MFMA16(ph.v, vv[5], O[qh][1]);
                O[qh][2] = MFMA16(ph.v, vv[6], O[qh][2]);
                O[qh][3] = MFMA16(ph.v, vv[7], O[qh][3]);
            }
        }

        // stage next tile into the other buffer (vmcnt wait auto-inserted)
        if (!last) {
            char* Kw = (char*)Ks + (size_t)((kt + 1) & 1) * 8192;
            char* Vw = (char*)Vs + (size_t)((kt + 1) & 1) * 10240;
            *(int4*)(Kw + kd0) = ka0;
            *(int4*)(Kw + kd1) = ka1;
            *(int4*)(Vw + vd0) = va0;
            *(int4*)(Vw + vd1) = va1;
        }
        __syncthreads();
    }

    // epilogue: l-reduce over quads (2 shuffles per half), then ctx = O / l
#pragma unroll
    for (int qh = 0; qh < 2; ++qh) {
        float ls = lsum[qh];
        ls += __shfl_xor(ls, 16);
        ls += __shfl_xor(ls, 32);
#pragma unroll
        for (int i = 0; i < 4; ++i) {
            float lt = __shfl(ls, quad * 4 + i);
            float inv = 1.0f / lt;
            int qi = qbase + qh * 16 + quad * 4 + i;
            float* op = ctx + ((size_t)(b * L + qi)) * D + h * 64;
#pragma unroll
            for (int fi = 0; fi < 4; ++fi) op[fi * 16 + l15] = O[qh][fi][i] * inv;
        }
    }
}

// ---------------- add + layernorm (one block per 1024-row) ----------------
__global__ __launch_bounds__(256) void k_add_ln(const float* __restrict__ X,
                                                const float* __restrict__ Y,
                                                const float* __restrict__ w,
                                                const float* __restrict__ bvec,
                                                float* __restrict__ outf,
                                                unsigned short* __restrict__ outbf) {
    int row = blockIdx.x;
    int tid = threadIdx.x;
    float4 x = *((const float4*)(X + (size_t)row * 1024) + tid);
    float4 y = *((const float4*)(Y + (size_t)row * 1024) + tid);
    float v0 = x.x + y.x, v1 = x.y + y.y, v2 = x.z + y.z, v3 = x.w + y.w;
    float s = v0 + v1 + v2 + v3;
    float s2 = v0 * v0 + v1 * v1 + v2 * v2 + v3 * v3;
#pragma unroll
    for (int off = 32; off > 0; off >>= 1) {
        s += __shfl_xor(s, off);
        s2 += __shfl_xor(s2, off);
    }
    __shared__ float red[8];
    int wave = tid >> 6, lane = tid & 63;
    if (lane == 0) { red[wave] = s; red[4 + wave] = s2; }
    __syncthreads();
    s = red[0] + red[1] + red[2] + red[3];
    s2 = red[4] + red[5] + red[6] + red[7];
    float u = s * (1.0f / 1024.0f);
    float var = s2 * (1.0f / 1024.0f) - u * u;
    float r = 1.0f / sqrtf(fmaxf(var, 0.0f) + 1e-12f);
    float4 wv = *((const float4*)w + tid);
    float4 bv = *((const float4*)bvec + tid);
    float o0 = wv.x * (v0 - u) * r + bv.x;
    float o1 = wv.y * (v1 - u) * r + bv.y;
    float o2 = wv.z * (v2 - u) * r + bv.z;
    float o3 = wv.w * (v3 - u) * r + bv.w;
    float4 o = {o0, o1, o2, o3};
    *((float4*)(outf + (size_t)row * 1024) + tid) = o;
    if (outbf) {
        ushortx4 ob;
        ob[0] = f2bf(o0); ob[1] = f2bf(o1); ob[2] = f2bf(o2); ob[3] = f2bf(o3);
        *((ushortx4*)outbf + (size_t)row * 256 + tid) = ob;
    }
}

// ---------------- host ----------------
extern "C" void kernel_launch(void* const* d_in, const int* in_sizes, int n_in,
                              void* d_out, int out_size, void* d_ws, size_t ws_size,
                              hipStream_t stream) {
    (void)in_sizes; (void)n_in; (void)out_size; (void)ws_size;
    const float* dec = (const float*)d_in[0];
    const float* enc = (const float*)d_in[1];
    const float* dec_mask = (const float*)d_in[2];
    const float* enc_mask = (const float*)d_in[3];
    const float* b_saq = (const float*)d_in[11];
    const float* b_sak = (const float*)d_in[12];
    const float* b_sav = (const float*)d_in[13];
    const float* b_caq = (const float*)d_in[14];
    const float* b_cak = (const float*)d_in[15];
    const float* b_cav = (const float*)d_in[16];
    const float* b_out = (const float*)d_in[17];
    const float* n1_b = (const float*)d_in[18];
    const float* n2_b = (const float*)d_in[19];
    const float* oln_b = (const float*)d_in[20];
    const float* n1_w = (const float*)d_in[21];
    const float* n2_w = (const float*)d_in[22];
    const float* oln_w = (const float*)d_in[23];

    char* ws = (char*)d_ws;
    const size_t MB2 = 2097152;       // 1M bf16
    const size_t ACT_BF = 8388608;    // 4M bf16
    const size_t ACT_F32 = 16777216;  // 4M f32
    unsigned short* Wbf[7];
    for (int i = 0; i < 7; ++i) Wbf[i] = (unsigned short*)(ws + i * MB2);
    size_t off = 7 * MB2;
    unsigned short* Xbf = (unsigned short*)(ws + off); off += ACT_BF;   // Xbf,Ebf contiguous
    unsigned short* Ebf = (unsigned short*)(ws + off); off += ACT_BF;
    unsigned short* Abf = (unsigned short*)(ws + off); off += ACT_BF;
    unsigned short* Cbf = (unsigned short*)(ws + off); off += ACT_BF;
    unsigned short* Qp = (unsigned short*)(ws + off); off += ACT_BF;
    unsigned short* Kp = (unsigned short*)(ws + off); off += ACT_BF;
    unsigned short* Vp = (unsigned short*)(ws + off); off += ACT_BF;
    float* ctx = (float*)(ws + off); off += ACT_F32;   // reused as h
    float* a_f32 = (float*)(ws + off); off += ACT_F32;
    float* c_f32 = (float*)(ws + off); off += ACT_F32;
    float* h_f32 = ctx;
    float* outp = (float*)d_out;

    dim3 blk(256);
    dim3 attn_grid(512);

    SrcAll sa;
    sa.a[0] = dec; sa.a[1] = enc;
    for (int i = 0; i < 7; ++i) sa.w[i] = (const float*)d_in[4 + i];
    k_conv<<<dim3(7680), blk, 0, stream>>>(sa, Xbf, Wbf[0]);

    // ---- self attention: fused QKV GEMM (N=3072) ----
    k_gemm_bias<0><<<dim3(32, 24), blk, 0, stream>>>(Xbf, Xbf, Wbf[0], b_saq, b_sak, b_sav,
                                                     Qp, Kp, Vp, 1024);
    k_flash_attn<<<attn_grid, blk, 0, stream>>>(Qp, Kp, Vp, dec_mask, ctx, 1);
    k_add_ln<<<dim3(4096), blk, 0, stream>>>(ctx, dec, n1_w, n1_b, a_f32, Abf);

    // ---- cross attention: fused Q(from A) + KV(from E) GEMM (N=3072) ----
    k_gemm_bias<4><<<dim3(32, 24), blk, 0, stream>>>(Abf, Ebf, Wbf[3], b_caq, b_cak, b_cav,
                                                     Qp, Kp, Vp, 1024);
    k_flash_attn<<<attn_grid, blk, 0, stream>>>(Qp, Kp, Vp, enc_mask, ctx, 0);
    k_add_ln<<<dim3(4096), blk, 0, stream>>>(a_f32, ctx, n2_w, n2_b, c_f32, Cbf);

    // ---- output dense + final LN ----
    k_gemm_bias<3><<<dim3(32, 8), blk, 0, stream>>>(Cbf, Cbf, Wbf[6], b_out, b_out, b_out,
                                                    h_f32, nullptr, nullptr, 1024);
    k_add_ln<<<dim3(4096), blk, 0, stream>>>(h_f32, c_f32, oln_w, oln_b, outp, (unsigned short*)nullptr);
}

// Round 10
// 344.978 us; speedup vs baseline: 1.0406x; 1.0406x over previous
//
#include <hip/hip_runtime.h>
#include <cstdint>
#include <cstddef>

// ---------------- types ----------------
typedef __bf16 bf16x8 __attribute__((ext_vector_type(8)));
typedef float  floatx4 __attribute__((ext_vector_type(4)));
typedef unsigned short ushortx8 __attribute__((ext_vector_type(8)));
typedef unsigned short ushortx4 __attribute__((ext_vector_type(4)));

#define MFMA16(a, b, c) __builtin_amdgcn_mfma_f32_16x16x32_bf16((a), (b), (c), 0, 0, 0)

__device__ inline unsigned short f2bf(float f) {
    unsigned int u = __float_as_uint(f);
    unsigned int r = (u + 0x7fffu + ((u >> 16) & 1u)) >> 16;
    return (unsigned short)r;
}

// ---------------- merged convert: activations (2 tensors) + weights (7) ----------------
struct SrcAll { const float* a[2]; const float* w[7]; };
__global__ __launch_bounds__(256) void k_conv(SrcAll s, unsigned short* __restrict__ adst,
                                              unsigned short* __restrict__ wdst) {
    int bid = blockIdx.x;
    if (bid < 4096) {               // activations: 1M i-units, 8 f32 each
        int i = bid * 256 + threadIdx.x;
        const float* src = s.a[i >> 19];
        int off = i & 524287;
        const float4* p = (const float4*)src + (size_t)off * 2;
        float4 x0 = p[0], x1 = p[1];
        ushortx8 o;
        o[0] = f2bf(x0.x); o[1] = f2bf(x0.y); o[2] = f2bf(x0.z); o[3] = f2bf(x0.w);
        o[4] = f2bf(x1.x); o[5] = f2bf(x1.y); o[6] = f2bf(x1.z); o[7] = f2bf(x1.w);
        *((ushortx8*)adst + i) = o;
    } else {                        // weights: 917504 i-units
        int i = (bid - 4096) * 256 + threadIdx.x;
        const float* src = s.w[i >> 17];
        int off = i & 131071;
        const float4* p = (const float4*)src + (size_t)off * 2;
        float4 x0 = p[0], x1 = p[1];
        ushortx8 o;
        o[0] = f2bf(x0.x); o[1] = f2bf(x0.y); o[2] = f2bf(x0.z); o[3] = f2bf(x0.w);
        o[4] = f2bf(x1.x); o[5] = f2bf(x1.y); o[6] = f2bf(x1.z); o[7] = f2bf(x1.w);
        *((ushortx8*)wdst + i) = o;
    }
}

// ---------------- GEMM: C[M][Nc] = A[M][K] @ W[Nc][K]^T + bias ----------------
// Round-10: tile 128m x 64n (was 128x128), BK=64, same ROUND-2 sync structure
// (frozen: reg-staged prefetch after compute barrier; DMA r3/r4/r6 and LDS
// swizzle r9 all regressed). Rationale: QKV grid was 768 = 3 blocks/CU
// (out-GEMM 256 = 1/CU) -- stall-exposed. 64-wide n-tiles: LDS 24KB -> 6
// blocks/CU, grid 1536 (QKV) / 512 (out), 24 waves/CU of TLP.
// A-side XCD-pinned stripe (L2 reuse, FETCH ~53MB) unchanged.
// MODE 0: fused QKV packs; MODE 3: f32 row-major; MODE 4: fused cross QKV
// (sect 0 uses A, sects 1-2 use A2).
// Pack layouts: Q/K[b][h][l][64] bf16; V[b][h][l/32][d(64)][l%32] bf16.
// Per wave: 64m x 32n sub-tile, acc[4][2], 16 MFMA per K-step.
template <int MODE>
__global__ __launch_bounds__(256) void k_gemm_bias(const unsigned short* __restrict__ A,
                                                   const unsigned short* __restrict__ A2,
                                                   const unsigned short* __restrict__ W,
                                                   const float* __restrict__ bias0,
                                                   const float* __restrict__ bias1,
                                                   const float* __restrict__ bias2,
                                                   void* __restrict__ d0,
                                                   void* __restrict__ d1,
                                                   void* __restrict__ d2,
                                                   int K) {
    __shared__ __align__(16) unsigned short As[128 * 64];   // 16 KB: [khalf][row128][32k]
    __shared__ __align__(16) unsigned short Bs[64 * 64];    // 8 KB:  [khalf][row64][32k]
    const int tid = threadIdx.x;
    const int wave = tid >> 6, lane = tid & 63;
    const int quad = lane >> 4, l15 = lane & 15;
    const int wm = wave >> 1, wn = wave & 1;

    constexpr int NT = (MODE == 3) ? 16 : 48;    // 64-wide n-tiles in grid
    int fid = blockIdx.y * 32 + blockIdx.x;
    int xcd = fid & 7, idx = fid >> 3;
    const int m0 = (xcd * 4 + idx / NT) * 128;
    const int n0 = (idx % NT) * 64;
    const int sect_blk = n0 >> 10;

    const unsigned short* Ause = (MODE == 4 && sect_blk != 0) ? A2 : A;

    const size_t rowbytes = (size_t)K * 2;
    const int idx0 = tid, idx1 = 256 + tid;
    const char* pA0 = (const char*)Ause + (size_t)(m0 + (idx0 >> 2)) * rowbytes + ((idx0 & 3) << 4);
    const char* pA1 = (const char*)Ause + (size_t)(m0 + (idx1 >> 2)) * rowbytes + ((idx1 & 3) << 4);
    const char* pB0 = (const char*)W + (size_t)(n0 + (tid >> 2)) * rowbytes + ((tid & 3) << 4);

    int4 a0a = *(const int4*)pA0, a0b = *(const int4*)(pA0 + 64);
    int4 a1a = *(const int4*)pA1, a1b = *(const int4*)(pA1 + 64);
    int4 b0a = *(const int4*)pB0, b0b = *(const int4*)(pB0 + 64);

    floatx4 acc[4][2] = {};

    const int KT = K >> 6;   // 16
    for (int kt = 0; kt < KT; ++kt) {
        __syncthreads();
        // A: [khalf 8192B][row*64 + seg*16]; B: [khalf 4096B][row*64 + seg*16]
        ((int4*)As)[idx0] = a0a; ((int4*)As)[idx1] = a1a;
        ((int4*)As)[512 + idx0] = a0b; ((int4*)As)[512 + idx1] = a1b;
        ((int4*)Bs)[tid] = b0a;
        ((int4*)Bs)[256 + tid] = b0b;
        __syncthreads();
        if (kt + 1 < KT) {   // prefetch next K-tile (in flight across the MFMAs)
            pA0 += 128; pA1 += 128; pB0 += 128;
            a0a = *(const int4*)pA0; a0b = *(const int4*)(pA0 + 64);
            a1a = *(const int4*)pA1; a1b = *(const int4*)(pA1 + 64);
            b0a = *(const int4*)pB0; b0b = *(const int4*)(pB0 + 64);
        }
        const char* Asb = (const char*)As;
        const char* Bsb = (const char*)Bs;
#pragma unroll
        for (int half = 0; half < 2; ++half) {
            const int hbA = half * 8192;
            const int hbB = half * 4096;
            bf16x8 af[4], bfr[2];
#pragma unroll
            for (int r = 0; r < 4; ++r)
                af[r] = *(const bf16x8*)(Asb + hbA + ((wm * 64 + r * 16 + l15) * 64 + quad * 16));
#pragma unroll
            for (int c = 0; c < 2; ++c)
                bfr[c] = *(const bf16x8*)(Bsb + hbB + ((wn * 32 + c * 16 + l15) * 64 + quad * 16));
#pragma unroll
            for (int r = 0; r < 4; ++r)
#pragma unroll
                for (int c = 0; c < 2; ++c)
                    acc[r][c] = MFMA16(af[r], bfr[c], acc[r][c]);
        }
    }

    // epilogue: C row = quad*4+i, col = l15
#pragma unroll
    for (int c = 0; c < 2; ++c) {
        int col = n0 + wn * 32 + c * 16 + l15;
        int sect = col >> 10, cc = col & 1023;
        float bv;
        if (MODE == 3) bv = bias0[col];
        else bv = (sect == 0 ? bias0 : (sect == 1 ? bias1 : bias2))[cc];
        int h = cc >> 6, d = cc & 63;
#pragma unroll
        for (int r = 0; r < 4; ++r) {
            int mrow = m0 + wm * 64 + r * 16 + quad * 4;
#pragma unroll
            for (int i = 0; i < 4; ++i) {
                float v = acc[r][c][i] + bv;
                int row = mrow + i;
                if (MODE == 3) {
                    ((float*)d0)[(size_t)row * 1024 + col] = v;
                } else {
                    int b = row >> 10, l = row & 1023;
                    unsigned short* base = (unsigned short*)(sect == 0 ? d0 : (sect == 1 ? d1 : d2));
                    bool isV = (sect == 2);
                    size_t off;
                    if (isV) {
                        int kk = l & 31;   // natural key order
                        off = (size_t)(b * 16 + h) * 65536 + (size_t)(l >> 5) * 2048 + d * 32 + kk;
                    } else {
                        off = ((size_t)(b * 16 + h) * 1024 + l) * 64 + d;
                    }
                    base[off] = f2bf(v);
                }
            }
        }
    }
}

// ---------------- flash attention v9 ----------------
// Qp,Kp: [b][h][1024][64] bf16; Vp: [b][h][32][64][32] bf16; mask: [b][1024] f32.
// v9 = v5's geometry (32 q-rows/wave, grid 512) x v7's in-register softmax
// (swapped QK^T + permlane P-transpose, no Plds). v8 (no LDS) proved staging
// is needed (95us latency-bound). K/V double-buffered, one __syncthreads per
// tile. LDS = 2x8K (K, XOR-swizzled) + 2x10K (V, 80B rows) + 4K (penf) = 40KB.
// f bits [g:3][q:3][x:3]: bh = x + 8g (XCD-pinned), qt = (q+g)&7, causal
// ktiles = 2qt+2 with wave-level and half-level skips.
__global__ __launch_bounds__(256, 2) void k_flash_attn(const unsigned short* __restrict__ Qp,
                                                       const unsigned short* __restrict__ Kp,
                                                       const unsigned short* __restrict__ Vp,
                                                       const float* __restrict__ mask,
                                                       float* __restrict__ ctx,
                                                       int causal) {
    const int L = 1024, D = 1024;
    const float SC = 0.18033688011112042f;      // 0.125 * log2(e)
    int f = blockIdx.x;                          // 0..511
    int g = f >> 6;                              // 0..7
    int bh = (f & 7) + (g << 3);                 // 0..63, XCD-pinned K/V
    int qt = ((f >> 3) + g) & 7;                 // causal balance spread
    int h = bh & 15, b = bh >> 4;
    int tid = threadIdx.x;
    int wave = tid >> 6, lane = tid & 63, quad = lane >> 4, l15 = lane & 15;
    int qbase = qt * 128 + wave * 32;            // 32 q rows per wave

    __shared__ __align__(16) unsigned short Ks[2 * 4096];   // 16 KB, XOR-swizzled rows
    __shared__ __align__(16) unsigned short Vs[2 * 5120];   // 20 KB, rows padded 80B
    __shared__ float penf[1024];                            // 4 KB

    {   // mask penalty, pre-scaled for exp2
        float4 mv = ((const float4*)(mask + b * L))[tid];
        float4 pv;
        pv.x = (1.0f - mv.x) * -14426.950408889634f;
        pv.y = (1.0f - mv.y) * -14426.950408889634f;
        pv.z = (1.0f - mv.z) * -14426.950408889634f;
        pv.w = (1.0f - mv.w) * -14426.950408889634f;
        ((float4*)penf)[tid] = pv;
    }

    // Q fragments: 32 q rows = 2 halves x 2 d-chunks
    const unsigned short* Qh = Qp + ((size_t)(b * 16 + h) * 1024 + qbase) * 64;
    bf16x8 qf[2][2];
#pragma unroll
    for (int qh = 0; qh < 2; ++qh) {
        qf[qh][0] = *(const bf16x8*)(Qh + (qh * 16 + l15) * 64 + quad * 8);
        qf[qh][1] = *(const bf16x8*)(Qh + (qh * 16 + l15) * 64 + 32 + quad * 8);
    }

    const char* Kh = (const char*)(Kp + (size_t)(b * 16 + h) * 65536);
    const char* Vh = (const char*)(Vp + (size_t)(b * 16 + h) * 65536);

    int ktiles = causal ? (2 * qt + 2) : 16;   // block-uniform

    // staging dests (within one buffer)
    int krow = tid >> 3, kblk = tid & 7;
    int kd0 = krow * 128 + ((kblk ^ (krow & 7)) << 4);
    int kd1 = kd0 + 4096;
    int vd0 = (tid >> 2) * 80 + ((tid & 3) << 4);
    int vd1 = vd0 + 5120;

    // fragment read offsets (within one buffer)
    int karA[4], karB[4];
#pragma unroll
    for (int r = 0; r < 4; ++r) {
        int row = r * 16 + l15;
        karA[r] = row * 128 + ((quad ^ (l15 & 7)) << 4);
        karB[r] = row * 128 + (((quad | 4) ^ (l15 & 7)) << 4);
    }
    int var_[8];
#pragma unroll
    for (int s = 0; s < 2; ++s)
#pragma unroll
        for (int fi = 0; fi < 4; ++fi)
            var_[s * 4 + fi] = s * 5120 + (fi * 16 + l15) * 80 + (quad << 4);

    floatx4 O[2][4] = {};
    float lsum[2] = {0.0f, 0.0f};

    // prologue: load + stage tile 0 into buffer 0
    int4 ka0 = *(const int4*)(Kh + tid * 16);
    int4 ka1 = *(const int4*)(Kh + 4096 + tid * 16);
    int4 va0 = *(const int4*)(Vh + tid * 16);
    int4 va1 = *(const int4*)(Vh + 4096 + tid * 16);
    {
        char* Kw = (char*)Ks;
        char* Vw = (char*)Vs;
        *(int4*)(Kw + kd0) = ka0;
        *(int4*)(Kw + kd1) = ka1;
        *(int4*)(Vw + vd0) = va0;
        *(int4*)(Vw + vd1) = va1;
    }
    __syncthreads();

    for (int kt = 0; kt < ktiles; ++kt) {
        const char* Ksb = (const char*)Ks + (size_t)(kt & 1) * 8192;
        const char* Vsb = (const char*)Vs + (size_t)(kt & 1) * 10240;
        int k0 = kt * 64;
        bool last = (kt + 1 >= ktiles);
        bool vis = !(causal && k0 > qbase + 31);   // wave-uniform: any visible keys?

        bf16x8 kA[4], kB[4], vv[8];
        if (vis) {
#pragma unroll
            for (int r = 0; r < 4; ++r) {
                kA[r] = *(const bf16x8*)(Ksb + karA[r]);
                kB[r] = *(const bf16x8*)(Ksb + karB[r]);
            }
#pragma unroll
            for (int s = 0; s < 8; ++s) vv[s] = *(const bf16x8*)(Vsb + var_[s]);
        }

        // prefetch next tile into regs (latency hidden under compute)
        if (!last) {
            const char* Kg = Kh + (size_t)(kt + 1) * 8192;
            const char* Vg = Vh + (size_t)(kt + 1) * 8192;
            ka0 = *(const int4*)(Kg + tid * 16);
            ka1 = *(const int4*)(Kg + 4096 + tid * 16);
            va0 = *(const int4*)(Vg + tid * 16);
            va1 = *(const int4*)(Vg + 4096 + tid * 16);
        }

        if (vis) {
#pragma unroll
            for (int qh = 0; qh < 2; ++qh) {
                int qlo = qbase + qh * 16;
                if (causal && k0 > qlo + 15) continue;       // half fully masked
                bool boundary = causal && (k0 + 63 > qlo);
                int qv = qlo + l15;

                // swapped QK^T: T[s] rows = keys 16s.., cols = q (lane l15)
                floatx4 T[4] = {};
                T[0] = MFMA16(kA[0], qf[qh][0], T[0]); T[0] = MFMA16(kB[0], qf[qh][1], T[0]);
                T[1] = MFMA16(kA[1], qf[qh][0], T[1]); T[1] = MFMA16(kB[1], qf[qh][1], T[1]);
                T[2] = MFMA16(kA[2], qf[qh][0], T[2]); T[2] = MFMA16(kB[2], qf[qh][1], T[2]);
                T[3] = MFMA16(kA[3], qf[qh][0], T[3]); T[3] = MFMA16(kB[3], qf[qh][1], T[3]);

                // softmax, fully lane-local; pack P to bf16 pairs per key-group s
                unsigned w_[4][2];
#pragma unroll
                for (int s = 0; s < 4; ++s) {
                    floatx4 pr = *(const floatx4*)(penf + k0 + 16 * s + quad * 4);
                    unsigned rr[4];
#pragma unroll
                    for (int i = 0; i < 4; ++i) {
                        float x = fmaf(T[s][i], SC, pr[i]);
                        if (boundary) {
                            int key = k0 + 16 * s + quad * 4 + i;
                            x = (key <= qv) ? x : -50000.0f;
                        }
                        float p = __builtin_amdgcn_exp2f(x);
                        lsum[qh] += p;
                        rr[i] = __float_as_uint(p) + 0x8000u;
                    }
                    w_[s][0] = __builtin_amdgcn_perm(rr[1], rr[0], 0x07060302u);
                    w_[s][1] = __builtin_amdgcn_perm(rr[3], rr[2], 0x07060302u);
                }

                // in-register transpose of P into PV A-fragment layout
                unsigned a00 = w_[0][0], a10 = w_[1][0];
                unsigned a01 = w_[0][1], a11 = w_[1][1];
                unsigned a20 = w_[2][0], a30 = w_[3][0];
                unsigned a21 = w_[2][1], a31 = w_[3][1];
                asm("v_permlane32_swap_b32 %0, %1" : "+v"(a00), "+v"(a10));
                asm("v_permlane32_swap_b32 %0, %1" : "+v"(a01), "+v"(a11));
                asm("v_permlane32_swap_b32 %0, %1" : "+v"(a20), "+v"(a30));
                asm("v_permlane32_swap_b32 %0, %1" : "+v"(a21), "+v"(a31));
                asm("v_permlane16_swap_b32 %0, %1" : "+v"(a00), "+v"(a10));
                asm("v_permlane16_swap_b32 %0, %1" : "+v"(a01), "+v"(a11));
                asm("v_permlane16_swap_b32 %0, %1" : "+v"(a20), "+v"(a30));
                asm("v_permlane16_swap_b32 %0, %1" : "+v"(a21), "+v"(a31));
                union PU { unsigned u[4]; bf16x8 v; };
                PU pl, ph;
                pl.u[0] = a00; pl.u[1] = a01; pl.u[2] = a10; pl.u[3] = a11;   // keys 0..31
                ph.u[0] = a20; ph.u[1] = a21; ph.u[2] = a30; ph.u[3] = a31;   // keys 32..63

                O[qh][0] = MFMA16(pl.v, vv[0], O[qh][0]);
                O[qh][1] = MFMA16(pl.v, vv[1], O[qh][1]);
                O[qh][2] = MFMA16(pl.v, vv[2], O[qh][2]);
                O[qh][3] = MFMA16(pl.v, vv[3], O[qh][3]);
                O[qh][0] = MFMA16(ph.v, vv[4], O[qh][0]);
                O[qh][1] = MFMA16(ph.v, vv[5], O[qh][1]);
                O[qh][2] = MFMA16(ph.v, vv[6], O[qh][2]);
                O[qh][3] = MFMA16(ph.v, vv[7], O[qh][3]);
            }
        }

        // stage next tile into the other buffer (vmcnt wait auto-inserted)
        if (!last) {
            char* Kw = (char*)Ks + (size_t)((kt + 1) & 1) * 8192;
            char* Vw = (char*)Vs + (size_t)((kt + 1) & 1) * 10240;
            *(int4*)(Kw + kd0) = ka0;
            *(int4*)(Kw + kd1) = ka1;
            *(int4*)(Vw + vd0) = va0;
            *(int4*)(Vw + vd1) = va1;
        }
        __syncthreads();
    }

    // epilogue: l-reduce over quads (2 shuffles per half), then ctx = O / l
#pragma unroll
    for (int qh = 0; qh < 2; ++qh) {
        float ls = lsum[qh];
        ls += __shfl_xor(ls, 16);
        ls += __shfl_xor(ls, 32);
#pragma unroll
        for (int i = 0; i < 4; ++i) {
            float lt = __shfl(ls, quad * 4 + i);
            float inv = 1.0f / lt;
            int qi = qbase + qh * 16 + quad * 4 + i;
            float* op = ctx + ((size_t)(b * L + qi)) * D + h * 64;
#pragma unroll
            for (int fi = 0; fi < 4; ++fi) op[fi * 16 + l15] = O[qh][fi][i] * inv;
        }
    }
}

// ---------------- add + layernorm (one block per 1024-row) ----------------
__global__ __launch_bounds__(256) void k_add_ln(const float* __restrict__ X,
                                                const float* __restrict__ Y,
                                                const float* __restrict__ w,
                                                const float* __restrict__ bvec,
                                                float* __restrict__ outf,
                                                unsigned short* __restrict__ outbf) {
    int row = blockIdx.x;
    int tid = threadIdx.x;
    float4 x = *((const float4*)(X + (size_t)row * 1024) + tid);
    float4 y = *((const float4*)(Y + (size_t)row * 1024) + tid);
    float v0 = x.x + y.x, v1 = x.y + y.y, v2 = x.z + y.z, v3 = x.w + y.w;
    float s = v0 + v1 + v2 + v3;
    float s2 = v0 * v0 + v1 * v1 + v2 * v2 + v3 * v3;
#pragma unroll
    for (int off = 32; off > 0; off >>= 1) {
        s += __shfl_xor(s, off);
        s2 += __shfl_xor(s2, off);
    }
    __shared__ float red[8];
    int wave = tid >> 6, lane = tid & 63;
    if (lane == 0) { red[wave] = s; red[4 + wave] = s2; }
    __syncthreads();
    s = red[0] + red[1] + red[2] + red[3];
    s2 = red[4] + red[5] + red[6] + red[7];
    float u = s * (1.0f / 1024.0f);
    float var = s2 * (1.0f / 1024.0f) - u * u;
    float r = 1.0f / sqrtf(fmaxf(var, 0.0f) + 1e-12f);
    float4 wv = *((const float4*)w + tid);
    float4 bv = *((const float4*)bvec + tid);
    float o0 = wv.x * (v0 - u) * r + bv.x;
    float o1 = wv.y * (v1 - u) * r + bv.y;
    float o2 = wv.z * (v2 - u) * r + bv.z;
    float o3 = wv.w * (v3 - u) * r + bv.w;
    float4 o = {o0, o1, o2, o3};
    *((float4*)(outf + (size_t)row * 1024) + tid) = o;
    if (outbf) {
        ushortx4 ob;
        ob[0] = f2bf(o0); ob[1] = f2bf(o1); ob[2] = f2bf(o2); ob[3] = f2bf(o3);
        *((ushortx4*)outbf + (size_t)row * 256 + tid) = ob;
    }
}

// ---------------- host ----------------
extern "C" void kernel_launch(void* const* d_in, const int* in_sizes, int n_in,
                              void* d_out, int out_size, void* d_ws, size_t ws_size,
                              hipStream_t stream) {
    (void)in_sizes; (void)n_in; (void)out_size; (void)ws_size;
    const float* dec = (const float*)d_in[0];
    const float* enc = (const float*)d_in[1];
    const float* dec_mask = (const float*)d_in[2];
    const float* enc_mask = (const float*)d_in[3];
    const float* b_saq = (const float*)d_in[11];
    const float* b_sak = (const float*)d_in[12];
    const float* b_sav = (const float*)d_in[13];
    const float* b_caq = (const float*)d_in[14];
    const float* b_cak = (const float*)d_in[15];
    const float* b_cav = (const float*)d_in[16];
    const float* b_out = (const float*)d_in[17];
    const float* n1_b = (const float*)d_in[18];
    const float* n2_b = (const float*)d_in[19];
    const float* oln_b = (const float*)d_in[20];
    const float* n1_w = (const float*)d_in[21];
    const float* n2_w = (const float*)d_in[22];
    const float* oln_w = (const float*)d_in[23];

    char* ws = (char*)d_ws;
    const size_t MB2 = 2097152;       // 1M bf16
    const size_t ACT_BF = 8388608;    // 4M bf16
    const size_t ACT_F32 = 16777216;  // 4M f32
    unsigned short* Wbf[7];
    for (int i = 0; i < 7; ++i) Wbf[i] = (unsigned short*)(ws + i * MB2);
    size_t off = 7 * MB2;
    unsigned short* Xbf = (unsigned short*)(ws + off); off += ACT_BF;   // Xbf,Ebf contiguous
    unsigned short* Ebf = (unsigned short*)(ws + off); off += ACT_BF;
    unsigned short* Abf = (unsigned short*)(ws + off); off += ACT_BF;
    unsigned short* Cbf = (unsigned short*)(ws + off); off += ACT_BF;
    unsigned short* Qp = (unsigned short*)(ws + off); off += ACT_BF;
    unsigned short* Kp = (unsigned short*)(ws + off); off += ACT_BF;
    unsigned short* Vp = (unsigned short*)(ws + off); off += ACT_BF;
    float* ctx = (float*)(ws + off); off += ACT_F32;   // reused as h
    float* a_f32 = (float*)(ws + off); off += ACT_F32;
    float* c_f32 = (float*)(ws + off); off += ACT_F32;
    float* h_f32 = ctx;
    float* outp = (float*)d_out;

    dim3 blk(256);
    dim3 attn_grid(512);

    SrcAll sa;
    sa.a[0] = dec; sa.a[1] = enc;
    for (int i = 0; i < 7; ++i) sa.w[i] = (const float*)d_in[4 + i];
    k_conv<<<dim3(7680), blk, 0, stream>>>(sa, Xbf, Wbf[0]);

    // ---- self attention: fused QKV GEMM (N=3072, 64-wide n-tiles) ----
    k_gemm_bias<0><<<dim3(32, 48), blk, 0, stream>>>(Xbf, Xbf, Wbf[0], b_saq, b_sak, b_sav,
                                                     Qp, Kp, Vp, 1024);
    k_flash_attn<<<attn_grid, blk, 0, stream>>>(Qp, Kp, Vp, dec_mask, ctx, 1);
    k_add_ln<<<dim3(4096), blk, 0, stream>>>(ctx, dec, n1_w, n1_b, a_f32, Abf);

    // ---- cross attention: fused Q(from A) + KV(from E) GEMM (N=3072) ----
    k_gemm_bias<4><<<dim3(32, 48), blk, 0, stream>>>(Abf, Ebf, Wbf[3], b_caq, b_cak, b_cav,
                                                     Qp, Kp, Vp, 1024);
    k_flash_attn<<<attn_grid, blk, 0, stream>>>(Qp, Kp, Vp, enc_mask, ctx, 0);
    k_add_ln<<<dim3(4096), blk, 0, stream>>>(a_f32, ctx, n2_w, n2_b, c_f32, Cbf);

    // ---- output dense + final LN ----
    k_gemm_bias<3><<<dim3(32, 16), blk, 0, stream>>>(Cbf, Cbf, Wbf[6], b_out, b_out, b_out,
                                                     h_f32, nullptr, nullptr, 1024);
    k_add_ln<<<dim3(4096), blk, 0, stream>>>(h_f32, c_f32, oln_w, oln_b, outp, (unsigned short*)nullptr);
}

// Round 11
// 321.612 us; speedup vs baseline: 1.1162x; 1.0727x over previous
//
#include <hip/hip_runtime.h>
#include <cstdint>
#include <cstddef>

// ---------------- types ----------------
typedef __bf16 bf16x8 __attribute__((ext_vector_type(8)));
typedef float  floatx4 __attribute__((ext_vector_type(4)));
typedef unsigned short ushortx8 __attribute__((ext_vector_type(8)));
typedef unsigned short ushortx4 __attribute__((ext_vector_type(4)));

#define MFMA16(a, b, c) __builtin_amdgcn_mfma_f32_16x16x32_bf16((a), (b), (c), 0, 0, 0)

__device__ inline unsigned short f2bf(float f) {
    unsigned int u = __float_as_uint(f);
    unsigned int r = (u + 0x7fffu + ((u >> 16) & 1u)) >> 16;
    return (unsigned short)r;
}

// ---------------- merged convert: activations (2 tensors) + weights (7) ----------------
struct SrcAll { const float* a[2]; const float* w[7]; };
__global__ __launch_bounds__(256) void k_conv(SrcAll s, unsigned short* __restrict__ adst,
                                              unsigned short* __restrict__ wdst) {
    int bid = blockIdx.x;
    if (bid < 4096) {               // activations: 1M i-units, 8 f32 each
        int i = bid * 256 + threadIdx.x;
        const float* src = s.a[i >> 19];
        int off = i & 524287;
        const float4* p = (const float4*)src + (size_t)off * 2;
        float4 x0 = p[0], x1 = p[1];
        ushortx8 o;
        o[0] = f2bf(x0.x); o[1] = f2bf(x0.y); o[2] = f2bf(x0.z); o[3] = f2bf(x0.w);
        o[4] = f2bf(x1.x); o[5] = f2bf(x1.y); o[6] = f2bf(x1.z); o[7] = f2bf(x1.w);
        *((ushortx8*)adst + i) = o;
    } else {                        // weights: 917504 i-units
        int i = (bid - 4096) * 256 + threadIdx.x;
        const float* src = s.w[i >> 17];
        int off = i & 131071;
        const float4* p = (const float4*)src + (size_t)off * 2;
        float4 x0 = p[0], x1 = p[1];
        ushortx8 o;
        o[0] = f2bf(x0.x); o[1] = f2bf(x0.y); o[2] = f2bf(x0.z); o[3] = f2bf(x0.w);
        o[4] = f2bf(x1.x); o[5] = f2bf(x1.y); o[6] = f2bf(x1.z); o[7] = f2bf(x1.w);
        *((ushortx8*)wdst + i) = o;
    }
}

// ---------------- GEMM: C[M][Nc] = A[M][K] @ W[Nc][K]^T + bias ----------------
// ROUND-2/8 VERIFIED STRUCTURE (42us/dispatch, 614 TF) -- FROZEN. Probed and
// rejected: DMA staging (r3/r4/r6), f32-A fusion (r5), LDS swizzle (r9,
// conflicts 3.1M->0 but dur 42->59: conflicts are hidden under the 2-barrier
// stall path, T2 regime gate), 128x64 tile (r10, 42->51: TLP didn't pay for
// lost fragment reuse). This structure+shape is at its stall-bound optimum.
// MODE 0: fused QKV packs; MODE 3: f32 row-major; MODE 4: fused cross QKV
// (sect 0 uses A, sects 1-2 use A2).
// Pack layouts: Q/K[b][h][l][64] bf16; V[b][h][l/32][d(64)][l%32] bf16.
// XCD swizzle: XCD (fid&7) owns a 4-m-tile stripe; streams the W n-tiles.
template <int MODE>
__global__ __launch_bounds__(256) void k_gemm_bias(const unsigned short* __restrict__ A,
                                                   const unsigned short* __restrict__ A2,
                                                   const unsigned short* __restrict__ W,
                                                   const float* __restrict__ bias0,
                                                   const float* __restrict__ bias1,
                                                   const float* __restrict__ bias2,
                                                   void* __restrict__ d0,
                                                   void* __restrict__ d1,
                                                   void* __restrict__ d2,
                                                   int K) {
    __shared__ __align__(16) unsigned short As[128 * 64];   // 16 KB
    __shared__ __align__(16) unsigned short Bs[128 * 64];   // 16 KB
    const int tid = threadIdx.x;
    const int wave = tid >> 6, lane = tid & 63;
    const int quad = lane >> 4, l15 = lane & 15;
    const int wm = wave >> 1, wn = wave & 1;

    constexpr int NT = (MODE == 3) ? 8 : 24;     // n-tiles in grid
    int fid = blockIdx.y * 32 + blockIdx.x;
    int xcd = fid & 7, idx = fid >> 3;
    const int m0 = (xcd * 4 + idx / NT) * 128;
    const int n0 = (idx % NT) * 128;
    const int sect_blk = n0 >> 10;

    const unsigned short* Ause = (MODE == 4 && sect_blk != 0) ? A2 : A;

    const size_t rowbytes = (size_t)K * 2;
    const int idx0 = tid, idx1 = 256 + tid;
    const char* pA0 = (const char*)Ause + (size_t)(m0 + (idx0 >> 2)) * rowbytes + ((idx0 & 3) << 4);
    const char* pA1 = (const char*)Ause + (size_t)(m0 + (idx1 >> 2)) * rowbytes + ((idx1 & 3) << 4);
    const char* pB0 = (const char*)W + (size_t)(n0 + (idx0 >> 2)) * rowbytes + ((idx0 & 3) << 4);
    const char* pB1 = (const char*)W + (size_t)(n0 + (idx1 >> 2)) * rowbytes + ((idx1 & 3) << 4);

    int4 a0a = *(const int4*)pA0, a0b = *(const int4*)(pA0 + 64);
    int4 a1a = *(const int4*)pA1, a1b = *(const int4*)(pA1 + 64);
    int4 b0a = *(const int4*)pB0, b0b = *(const int4*)(pB0 + 64);
    int4 b1a = *(const int4*)pB1, b1b = *(const int4*)(pB1 + 64);

    floatx4 acc[4][4] = {};

    const int KT = K >> 6;   // 16
    for (int kt = 0; kt < KT; ++kt) {
        __syncthreads();
        ((int4*)As)[idx0] = a0a; ((int4*)As)[idx1] = a1a;
        ((int4*)As)[512 + idx0] = a0b; ((int4*)As)[512 + idx1] = a1b;
        ((int4*)Bs)[idx0] = b0a; ((int4*)Bs)[idx1] = b1a;
        ((int4*)Bs)[512 + idx0] = b0b; ((int4*)Bs)[512 + idx1] = b1b;
        __syncthreads();
        if (kt + 1 < KT) {   // prefetch next K-tile (in flight across the MFMAs)
            pA0 += 128; pA1 += 128; pB0 += 128; pB1 += 128;
            a0a = *(const int4*)pA0; a0b = *(const int4*)(pA0 + 64);
            a1a = *(const int4*)pA1; a1b = *(const int4*)(pA1 + 64);
            b0a = *(const int4*)pB0; b0b = *(const int4*)(pB0 + 64);
            b1a = *(const int4*)pB1; b1b = *(const int4*)(pB1 + 64);
        }
        const char* Asb = (const char*)As;
        const char* Bsb = (const char*)Bs;
#pragma unroll
        for (int half = 0; half < 2; ++half) {
            const int hb = half * 8192;
            bf16x8 af[4], bfr[4];
#pragma unroll
            for (int r = 0; r < 4; ++r)
                af[r] = *(const bf16x8*)(Asb + hb + ((wm * 64 + r * 16 + l15) * 64 + quad * 16));
#pragma unroll
            for (int c = 0; c < 4; ++c)
                bfr[c] = *(const bf16x8*)(Bsb + hb + ((wn * 64 + c * 16 + l15) * 64 + quad * 16));
#pragma unroll
            for (int r = 0; r < 4; ++r)
#pragma unroll
                for (int c = 0; c < 4; ++c)
                    acc[r][c] = MFMA16(af[r], bfr[c], acc[r][c]);
        }
    }

    // epilogue: C row = quad*4+i, col = l15
#pragma unroll
    for (int c = 0; c < 4; ++c) {
        int col = n0 + wn * 64 + c * 16 + l15;
        int sect = col >> 10, cc = col & 1023;
        float bv;
        if (MODE == 3) bv = bias0[col];
        else bv = (sect == 0 ? bias0 : (sect == 1 ? bias1 : bias2))[cc];
        int h = cc >> 6, d = cc & 63;
#pragma unroll
        for (int r = 0; r < 4; ++r) {
            int mrow = m0 + wm * 64 + r * 16 + quad * 4;
#pragma unroll
            for (int i = 0; i < 4; ++i) {
                float v = acc[r][c][i] + bv;
                int row = mrow + i;
                if (MODE == 3) {
                    ((float*)d0)[(size_t)row * 1024 + col] = v;
                } else {
                    int b = row >> 10, l = row & 1023;
                    unsigned short* base = (unsigned short*)(sect == 0 ? d0 : (sect == 1 ? d1 : d2));
                    bool isV = (sect == 2);
                    size_t off;
                    if (isV) {
                        int kk = l & 31;   // natural key order
                        off = (size_t)(b * 16 + h) * 65536 + (size_t)(l >> 5) * 2048 + d * 32 + kk;
                    } else {
                        off = ((size_t)(b * 16 + h) * 1024 + l) * 64 + d;
                    }
                    base[off] = f2bf(v);
                }
            }
        }
    }
}

// ---------------- flash attention v9b ----------------
// Qp,Kp: [b][h][1024][64] bf16; Vp: [b][h][32][64][32] bf16; mask: [b][1024] f32.
// v9 = 32 q-rows/wave (grid 512) x in-register softmax (swapped QK^T +
// permlane P-transpose, no Plds). K/V double-buffered, one __syncthreads per
// tile. LDS = 2x8K (K, XOR-swizzled) + 2x10K (V, 80B rows) + 4K (penf) = 40KB.
// v9b: COMPLEMENTARY CAUSAL PAIRING. Self-attn and cross-attn timed equal
// despite 2x FLOP difference -> hypothesis: tile-phase-paced + per-CU
// imbalance. Old map gave co-resident blocks (i, i+256 -> same CU under
// round-robin, 256 = 8 XCD x 32 CU) qt pairs {q,q+4}: per-CU causal tile sums
// 12..24. New bijective map gives pairs (q, 7-q): constant sum 18.
//   qt8=(f>>3)&7; qt=(f&256)?7-qt8:qt8; bh=(f&7)|(((f>>6)&3)<<3)|(((f>>8)&1)<<5)
// XCD pinning preserved (bh low 3 bits = f&7). ktiles = 2qt+2.
__global__ __launch_bounds__(256, 2) void k_flash_attn(const unsigned short* __restrict__ Qp,
                                                       const unsigned short* __restrict__ Kp,
                                                       const unsigned short* __restrict__ Vp,
                                                       const float* __restrict__ mask,
                                                       float* __restrict__ ctx,
                                                       int causal) {
    const int L = 1024, D = 1024;
    const float SC = 0.18033688011112042f;      // 0.125 * log2(e)
    int f = blockIdx.x;                          // 0..511
    int qt8 = (f >> 3) & 7;
    int qt = (f & 256) ? (7 - qt8) : qt8;        // complementary pairing across CU partners
    int bh = (f & 7) | (((f >> 6) & 3) << 3) | (((f >> 8) & 1) << 5);   // 0..63, XCD-pinned
    int h = bh & 15, b = bh >> 4;
    int tid = threadIdx.x;
    int wave = tid >> 6, lane = tid & 63, quad = lane >> 4, l15 = lane & 15;
    int qbase = qt * 128 + wave * 32;            // 32 q rows per wave

    __shared__ __align__(16) unsigned short Ks[2 * 4096];   // 16 KB, XOR-swizzled rows
    __shared__ __align__(16) unsigned short Vs[2 * 5120];   // 20 KB, rows padded 80B
    __shared__ float penf[1024];                            // 4 KB

    {   // mask penalty, pre-scaled for exp2
        float4 mv = ((const float4*)(mask + b * L))[tid];
        float4 pv;
        pv.x = (1.0f - mv.x) * -14426.950408889634f;
        pv.y = (1.0f - mv.y) * -14426.950408889634f;
        pv.z = (1.0f - mv.z) * -14426.950408889634f;
        pv.w = (1.0f - mv.w) * -14426.950408889634f;
        ((float4*)penf)[tid] = pv;
    }

    // Q fragments: 32 q rows = 2 halves x 2 d-chunks
    const unsigned short* Qh = Qp + ((size_t)(b * 16 + h) * 1024 + qbase) * 64;
    bf16x8 qf[2][2];
#pragma unroll
    for (int qh = 0; qh < 2; ++qh) {
        qf[qh][0] = *(const bf16x8*)(Qh + (qh * 16 + l15) * 64 + quad * 8);
        qf[qh][1] = *(const bf16x8*)(Qh + (qh * 16 + l15) * 64 + 32 + quad * 8);
    }

    const char* Kh = (const char*)(Kp + (size_t)(b * 16 + h) * 65536);
    const char* Vh = (const char*)(Vp + (size_t)(b * 16 + h) * 65536);

    int ktiles = causal ? (2 * qt + 2) : 16;   // block-uniform

    // staging dests (within one buffer)
    int krow = tid >> 3, kblk = tid & 7;
    int kd0 = krow * 128 + ((kblk ^ (krow & 7)) << 4);
    int kd1 = kd0 + 4096;
    int vd0 = (tid >> 2) * 80 + ((tid & 3) << 4);
    int vd1 = vd0 + 5120;

    // fragment read offsets (within one buffer)
    int karA[4], karB[4];
#pragma unroll
    for (int r = 0; r < 4; ++r) {
        int row = r * 16 + l15;
        karA[r] = row * 128 + ((quad ^ (l15 & 7)) << 4);
        karB[r] = row * 128 + (((quad | 4) ^ (l15 & 7)) << 4);
    }
    int var_[8];
#pragma unroll
    for (int s = 0; s < 2; ++s)
#pragma unroll
        for (int fi = 0; fi < 4; ++fi)
            var_[s * 4 + fi] = s * 5120 + (fi * 16 + l15) * 80 + (quad << 4);

    floatx4 O[2][4] = {};
    float lsum[2] = {0.0f, 0.0f};

    // prologue: load + stage tile 0 into buffer 0
    int4 ka0 = *(const int4*)(Kh + tid * 16);
    int4 ka1 = *(const int4*)(Kh + 4096 + tid * 16);
    int4 va0 = *(const int4*)(Vh + tid * 16);
    int4 va1 = *(const int4*)(Vh + 4096 + tid * 16);
    {
        char* Kw = (char*)Ks;
        char* Vw = (char*)Vs;
        *(int4*)(Kw + kd0) = ka0;
        *(int4*)(Kw + kd1) = ka1;
        *(int4*)(Vw + vd0) = va0;
        *(int4*)(Vw + vd1) = va1;
    }
    __syncthreads();

    for (int kt = 0; kt < ktiles; ++kt) {
        const char* Ksb = (const char*)Ks + (size_t)(kt & 1) * 8192;
        const char* Vsb = (const char*)Vs + (size_t)(kt & 1) * 10240;
        int k0 = kt * 64;
        bool last = (kt + 1 >= ktiles);
        bool vis = !(causal && k0 > qbase + 31);   // wave-uniform: any visible keys?

        bf16x8 kA[4], kB[4], vv[8];
        if (vis) {
#pragma unroll
            for (int r = 0; r < 4; ++r) {
                kA[r] = *(const bf16x8*)(Ksb + karA[r]);
                kB[r] = *(const bf16x8*)(Ksb + karB[r]);
            }
#pragma unroll
            for (int s = 0; s < 8; ++s) vv[s] = *(const bf16x8*)(Vsb + var_[s]);
        }

        // prefetch next tile into regs (latency hidden under compute)
        if (!last) {
            const char* Kg = Kh + (size_t)(kt + 1) * 8192;
            const char* Vg = Vh + (size_t)(kt + 1) * 8192;
            ka0 = *(const int4*)(Kg + tid * 16);
            ka1 = *(const int4*)(Kg + 4096 + tid * 16);
            va0 = *(const int4*)(Vg + tid * 16);
            va1 = *(const int4*)(Vg + 4096 + tid * 16);
        }

        if (vis) {
#pragma unroll
            for (int qh = 0; qh < 2; ++qh) {
                int qlo = qbase + qh * 16;
                if (causal && k0 > qlo + 15) continue;       // half fully masked
                bool boundary = causal && (k0 + 63 > qlo);
                int qv = qlo + l15;

                // swapped QK^T: T[s] rows = keys 16s.., cols = q (lane l15)
                floatx4 T[4] = {};
                T[0] = MFMA16(kA[0], qf[qh][0], T[0]); T[0] = MFMA16(kB[0], qf[qh][1], T[0]);
                T[1] = MFMA16(kA[1], qf[qh][0], T[1]); T[1] = MFMA16(kB[1], qf[qh][1], T[1]);
                T[2] = MFMA16(kA[2], qf[qh][0], T[2]); T[2] = MFMA16(kB[2], qf[qh][1], T[2]);
                T[3] = MFMA16(kA[3], qf[qh][0], T[3]); T[3] = MFMA16(kB[3], qf[qh][1], T[3]);

                // softmax, fully lane-local; pack P to bf16 pairs per key-group s
                unsigned w_[4][2];
#pragma unroll
                for (int s = 0; s < 4; ++s) {
                    floatx4 pr = *(const floatx4*)(penf + k0 + 16 * s + quad * 4);
                    unsigned rr[4];
#pragma unroll
                    for (int i = 0; i < 4; ++i) {
                        float x = fmaf(T[s][i], SC, pr[i]);
                        if (boundary) {
                            int key = k0 + 16 * s + quad * 4 + i;
                            x = (key <= qv) ? x : -50000.0f;
                        }
                        float p = __builtin_amdgcn_exp2f(x);
                        lsum[qh] += p;
                        rr[i] = __float_as_uint(p) + 0x8000u;
                    }
                    w_[s][0] = __builtin_amdgcn_perm(rr[1], rr[0], 0x07060302u);
                    w_[s][1] = __builtin_amdgcn_perm(rr[3], rr[2], 0x07060302u);
                }

                // in-register transpose of P into PV A-fragment layout
                unsigned a00 = w_[0][0], a10 = w_[1][0];
                unsigned a01 = w_[0][1], a11 = w_[1][1];
                unsigned a20 = w_[2][0], a30 = w_[3][0];
                unsigned a21 = w_[2][1], a31 = w_[3][1];
                asm("v_permlane32_swap_b32 %0, %1" : "+v"(a00), "+v"(a10));
                asm("v_permlane32_swap_b32 %0, %1" : "+v"(a01), "+v"(a11));
                asm("v_permlane32_swap_b32 %0, %1" : "+v"(a20), "+v"(a30));
                asm("v_permlane32_swap_b32 %0, %1" : "+v"(a21), "+v"(a31));
                asm("v_permlane16_swap_b32 %0, %1" : "+v"(a00), "+v"(a10));
                asm("v_permlane16_swap_b32 %0, %1" : "+v"(a01), "+v"(a11));
                asm("v_permlane16_swap_b32 %0, %1" : "+v"(a20), "+v"(a30));
                asm("v_permlane16_swap_b32 %0, %1" : "+v"(a21), "+v"(a31));
                union PU { unsigned u[4]; bf16x8 v; };
                PU pl, ph;
                pl.u[0] = a00; pl.u[1] = a01; pl.u[2] = a10; pl.u[3] = a11;   // keys 0..31
                ph.u[0] = a20; ph.u[1] = a21; ph.u[2] = a30; ph.u[3] = a31;   // keys 32..63

                O[qh][0] = MFMA16(pl.v, vv[0], O[qh][0]);
                O[qh][1] = MFMA16(pl.v, vv[1], O[qh][1]);
                O[qh][2] = MFMA16(pl.v, vv[2], O[qh][2]);
                O[qh][3] = MFMA16(pl.v, vv[3], O[qh][3]);
                O[qh][0] = MFMA16(ph.v, vv[4], O[qh][0]);
                O[qh][1] = MFMA16(ph.v, vv[5], O[qh][1]);
                O[qh][2] = MFMA16(ph.v, vv[6], O[qh][2]);
                O[qh][3] = MFMA16(ph.v, vv[7], O[qh][3]);
            }
        }

        // stage next tile into the other buffer (vmcnt wait auto-inserted)
        if (!last) {
            char* Kw = (char*)Ks + (size_t)((kt + 1) & 1) * 8192;
            char* Vw = (char*)Vs + (size_t)((kt + 1) & 1) * 10240;
            *(int4*)(Kw + kd0) = ka0;
            *(int4*)(Kw + kd1) = ka1;
            *(int4*)(Vw + vd0) = va0;
            *(int4*)(Vw + vd1) = va1;
        }
        __syncthreads();
    }

    // epilogue: l-reduce over quads (2 shuffles per half), then ctx = O / l
#pragma unroll
    for (int qh = 0; qh < 2; ++qh) {
        float ls = lsum[qh];
        ls += __shfl_xor(ls, 16);
        ls += __shfl_xor(ls, 32);
#pragma unroll
        for (int i = 0; i < 4; ++i) {
            float lt = __shfl(ls, quad * 4 + i);
            float inv = 1.0f / lt;
            int qi = qbase + qh * 16 + quad * 4 + i;
            float* op = ctx + ((size_t)(b * L + qi)) * D + h * 64;
#pragma unroll
            for (int fi = 0; fi < 4; ++fi) op[fi * 16 + l15] = O[qh][fi][i] * inv;
        }
    }
}

// ---------------- add + layernorm (one block per 1024-row) ----------------
__global__ __launch_bounds__(256) void k_add_ln(const float* __restrict__ X,
                                                const float* __restrict__ Y,
                                                const float* __restrict__ w,
                                                const float* __restrict__ bvec,
                                                float* __restrict__ outf,
                                                unsigned short* __restrict__ outbf) {
    int row = blockIdx.x;
    int tid = threadIdx.x;
    float4 x = *((const float4*)(X + (size_t)row * 1024) + tid);
    float4 y = *((const float4*)(Y + (size_t)row * 1024) + tid);
    float v0 = x.x + y.x, v1 = x.y + y.y, v2 = x.z + y.z, v3 = x.w + y.w;
    float s = v0 + v1 + v2 + v3;
    float s2 = v0 * v0 + v1 * v1 + v2 * v2 + v3 * v3;
#pragma unroll
    for (int off = 32; off > 0; off >>= 1) {
        s += __shfl_xor(s, off);
        s2 += __shfl_xor(s2, off);
    }
    __shared__ float red[8];
    int wave = tid >> 6, lane = tid & 63;
    if (lane == 0) { red[wave] = s; red[4 + wave] = s2; }
    __syncthreads();
    s = red[0] + red[1] + red[2] + red[3];
    s2 = red[4] + red[5] + red[6] + red[7];
    float u = s * (1.0f / 1024.0f);
    float var = s2 * (1.0f / 1024.0f) - u * u;
    float r = 1.0f / sqrtf(fmaxf(var, 0.0f) + 1e-12f);
    float4 wv = *((const float4*)w + tid);
    float4 bv = *((const float4*)bvec + tid);
    float o0 = wv.x * (v0 - u) * r + bv.x;
    float o1 = wv.y * (v1 - u) * r + bv.y;
    float o2 = wv.z * (v2 - u) * r + bv.z;
    float o3 = wv.w * (v3 - u) * r + bv.w;
    float4 o = {o0, o1, o2, o3};
    *((float4*)(outf + (size_t)row * 1024) + tid) = o;
    if (outbf) {
        ushortx4 ob;
        ob[0] = f2bf(o0); ob[1] = f2bf(o1); ob[2] = f2bf(o2); ob[3] = f2bf(o3);
        *((ushortx4*)outbf + (size_t)row * 256 + tid) = ob;
    }
}

// ---------------- host ----------------
extern "C" void kernel_launch(void* const* d_in, const int* in_sizes, int n_in,
                              void* d_out, int out_size, void* d_ws, size_t ws_size,
                              hipStream_t stream) {
    (void)in_sizes; (void)n_in; (void)out_size; (void)ws_size;
    const float* dec = (const float*)d_in[0];
    const float* enc = (const float*)d_in[1];
    const float* dec_mask = (const float*)d_in[2];
    const float* enc_mask = (const float*)d_in[3];
    const float* b_saq = (const float*)d_in[11];
    const float* b_sak = (const float*)d_in[12];
    const float* b_sav = (const float*)d_in[13];
    const float* b_caq = (const float*)d_in[14];
    const float* b_cak = (const float*)d_in[15];
    const float* b_cav = (const float*)d_in[16];
    const float* b_out = (const float*)d_in[17];
    const float* n1_b = (const float*)d_in[18];
    const float* n2_b = (const float*)d_in[19];
    const float* oln_b = (const float*)d_in[20];
    const float* n1_w = (const float*)d_in[21];
    const float* n2_w = (const float*)d_in[22];
    const float* oln_w = (const float*)d_in[23];

    char* ws = (char*)d_ws;
    const size_t MB2 = 2097152;       // 1M bf16
    const size_t ACT_BF = 8388608;    // 4M bf16
    const size_t ACT_F32 = 16777216;  // 4M f32
    unsigned short* Wbf[7];
    for (int i = 0; i < 7; ++i) Wbf[i] = (unsigned short*)(ws + i * MB2);
    size_t off = 7 * MB2;
    unsigned short* Xbf = (unsigned short*)(ws + off); off += ACT_BF;   // Xbf,Ebf contiguous
    unsigned short* Ebf = (unsigned short*)(ws + off); off += ACT_BF;
    unsigned short* Abf = (unsigned short*)(ws + off); off += ACT_BF;
    unsigned short* Cbf = (unsigned short*)(ws + off); off += ACT_BF;
    unsigned short* Qp = (unsigned short*)(ws + off); off += ACT_BF;
    unsigned short* Kp = (unsigned short*)(ws + off); off += ACT_BF;
    unsigned short* Vp = (unsigned short*)(ws + off); off += ACT_BF;
    float* ctx = (float*)(ws + off); off += ACT_F32;   // reused as h
    float* a_f32 = (float*)(ws + off); off += ACT_F32;
    float* c_f32 = (float*)(ws + off); off += ACT_F32;
    float* h_f32 = ctx;
    float* outp = (float*)d_out;

    dim3 blk(256);
    dim3 attn_grid(512);

    SrcAll sa;
    sa.a[0] = dec; sa.a[1] = enc;
    for (int i = 0; i < 7; ++i) sa.w[i] = (const float*)d_in[4 + i];
    k_conv<<<dim3(7680), blk, 0, stream>>>(sa, Xbf, Wbf[0]);

    // ---- self attention: fused QKV GEMM (N=3072) ----
    k_gemm_bias<0><<<dim3(32, 24), blk, 0, stream>>>(Xbf, Xbf, Wbf[0], b_saq, b_sak, b_sav,
                                                     Qp, Kp, Vp, 1024);
    k_flash_attn<<<attn_grid, blk, 0, stream>>>(Qp, Kp, Vp, dec_mask, ctx, 1);
    k_add_ln<<<dim3(4096), blk, 0, stream>>>(ctx, dec, n1_w, n1_b, a_f32, Abf);

    // ---- cross attention: fused Q(from A) + KV(from E) GEMM (N=3072) ----
    k_gemm_bias<4><<<dim3(32, 24), blk, 0, stream>>>(Abf, Ebf, Wbf[3], b_caq, b_cak, b_cav,
                                                     Qp, Kp, Vp, 1024);
    k_flash_attn<<<attn_grid, blk, 0, stream>>>(Qp, Kp, Vp, enc_mask, ctx, 0);
    k_add_ln<<<dim3(4096), blk, 0, stream>>>(a_f32, ctx, n2_w, n2_b, c_f32, Cbf);

    // ---- output dense + final LN ----
    k_gemm_bias<3><<<dim3(32, 8), blk, 0, stream>>>(Cbf, Cbf, Wbf[6], b_out, b_out, b_out,
                                                    h_f32, nullptr, nullptr, 1024);
    k_add_ln<<<dim3(4096), blk, 0, stream>>>(h_f32, c_f32, oln_w, oln_b, outp, (unsigned short*)nullptr);
}